// Round 2
// baseline (195.411 us; speedup 1.0000x reference)
//
#include <hip/hip_runtime.h>
#include <stdint.h>

#define MARGIN 0.3f
#define M 1024
#define NG 32768
#define K 512
#define BM 128
#define BN 128
#define BK 64
#define KT (K / BK)     // 8 k-tiles
#define NT (NG / BN)    // 256 n-tiles
#define NPART (NT * 2)  // 512 partials per row (2 waves per n-tile)

typedef __attribute__((ext_vector_type(8))) __bf16 bf16x8;
typedef __attribute__((ext_vector_type(4))) float f32x4;
typedef unsigned short ushort_t;
typedef unsigned int uint_t;

// ---- f32 -> bf16 (RNE) ----
static __device__ __forceinline__ ushort_t f2bf(float f) {
    uint_t u = __float_as_uint(f);
    u += 0x7FFFu + ((u >> 16) & 1u);
    return (ushort_t)(u >> 16);
}

// fused convert of inputs (n8a chunks) and features (n8b chunks), 8 floats/chunk
__global__ __launch_bounds__(256) void cvt_kernel(const float* __restrict__ fa,
                                                  ushort_t* __restrict__ da, int n8a,
                                                  const float* __restrict__ fb,
                                                  ushort_t* __restrict__ db, int n8b) {
    const int stride = gridDim.x * 256;
    const int ntot = n8a + n8b;
    for (int i = blockIdx.x * 256 + threadIdx.x; i < ntot; i += stride) {
        const float4* s4;
        uint4* d4;
        int j;
        if (i < n8a) { s4 = (const float4*)fa; d4 = (uint4*)da; j = i; }
        else         { s4 = (const float4*)fb; d4 = (uint4*)db; j = i - n8a; }
        float4 a = s4[2 * j];
        float4 b = s4[2 * j + 1];
        uint4 o;
        o.x = (uint_t)f2bf(a.x) | ((uint_t)f2bf(a.y) << 16);
        o.y = (uint_t)f2bf(a.z) | ((uint_t)f2bf(a.w) << 16);
        o.z = (uint_t)f2bf(b.x) | ((uint_t)f2bf(b.y) << 16);
        o.w = (uint_t)f2bf(b.z) | ((uint_t)f2bf(b.w) << 16);
        d4[j] = o;
    }
}

// ---- async global->LDS, 16B per lane ----
static __device__ __forceinline__ void gload_lds16(const void* gptr, void* lptr) {
    __builtin_amdgcn_global_load_lds(
        (const __attribute__((address_space(1))) uint32_t*)(gptr),
        (__attribute__((address_space(3))) uint32_t*)(uintptr_t)(lptr),
        16, 0, 0);
}

// ---- fused GEMM + masked min/max partial reduction (2-phase dbuf) ----
__global__ __launch_bounds__(256) void gemm_kernel(
    const ushort_t* __restrict__ A,   // [1024][512] bf16
    const ushort_t* __restrict__ B,   // [32768][512] bf16
    const int* __restrict__ targets,  // [1024]
    const int* __restrict__ idxv,     // [1024]
    const int* __restrict__ labels,   // [32768]
    float* __restrict__ pos_part,     // [1024][NPART]
    float* __restrict__ neg_part) {   // [1024][NPART]

    __shared__ __align__(16) ushort_t sA[2][BM * BK];
    __shared__ __align__(16) ushort_t sB[2][BN * BK];
    __shared__ int t_s[BM];
    __shared__ int i_s[BM];
    __shared__ int l_s[BN];

    const int tid = threadIdx.x;
    const int lane = tid & 63;
    const int w = tid >> 6;       // wave 0..3
    const int wm = w >> 1;        // 0..1 (row half)
    const int wn = w & 1;         // 0..1 (col half)
    const int bid = blockIdx.x;
    // XCD colocation: same-ntile blocks are 256 apart -> same (bid mod 8) -> same XCD.
    const int ntile = bid & 255;
    const int mtile = bid >> 8;

    if (tid < BM) {
        t_s[tid] = targets[mtile * BM + tid];
        i_s[tid] = idxv[mtile * BM + tid];
    } else {
        l_s[tid - BM] = labels[ntile * BN + (tid - BM)];
    }

    f32x4 zero = {0.f, 0.f, 0.f, 0.f};
    f32x4 acc[4][4];
#pragma unroll
    for (int a = 0; a < 4; ++a)
#pragma unroll
        for (int b = 0; b < 4; ++b) acc[a][b] = zero;

    const int lrow8 = lane >> 3;        // 0..7
    const int lcol = (lane & 7) * 8;    // element col, 16B per lane
    const ushort_t* Abase = A + (size_t)mtile * BM * K;
    const ushort_t* Bbase = B + (size_t)ntile * BN * K;

    auto stage = [&](int buf, int kt) {
        const int kk = kt * BK;
#pragma unroll
        for (int i = 0; i < 4; ++i) {
            const int c = i * 4 + w;          // wave-uniform chunk id
            const int row = c * 8 + lrow8;
            gload_lds16(&Abase[(size_t)row * K + kk + lcol], &sA[buf][c * 512]);
            gload_lds16(&Bbase[(size_t)row * K + kk + lcol], &sB[buf][c * 512]);
        }
    };

    // prologue: stage tile 0, drain
    stage(0, 0);
    __syncthreads();

    int cur = 0;
#pragma unroll 1
    for (int kt = 0; kt < KT; ++kt) {
        if (kt + 1 < KT) stage(cur ^ 1, kt + 1);   // overlap load(kt+1) with compute(kt)
#pragma unroll
        for (int k2 = 0; k2 < 2; ++k2) {
            bf16x8 av[4], bv[4];
#pragma unroll
            for (int mf = 0; mf < 4; ++mf)
                av[mf] = *(const bf16x8*)&sA[cur][(wm * 64 + mf * 16 + (lane & 15)) * BK + k2 * 32 + (lane >> 4) * 8];
#pragma unroll
            for (int nf = 0; nf < 4; ++nf)
                bv[nf] = *(const bf16x8*)&sB[cur][(wn * 64 + nf * 16 + (lane & 15)) * BK + k2 * 32 + (lane >> 4) * 8];
#pragma unroll
            for (int mf = 0; mf < 4; ++mf)
#pragma unroll
                for (int nf = 0; nf < 4; ++nf)
                    acc[mf][nf] = __builtin_amdgcn_mfma_f32_16x16x32_bf16(av[mf], bv[nf], acc[mf][nf], 0, 0, 0);
        }
        __syncthreads();   // drains lgkm + vmcnt(0): stage(kt+1) lands, buf swap safe
        cur ^= 1;
    }

    // ---- epilogue: masked min/max over this wave's 64-col stripe ----
    const int l15 = lane & 15;
    const int lhi = lane >> 4;
    int labv[4], jv[4];
#pragma unroll
    for (int nf = 0; nf < 4; ++nf) {
        const int cl = wn * 64 + nf * 16 + l15;
        labv[nf] = l_s[cl];
        jv[nf] = ntile * BN + cl;
    }
#pragma unroll
    for (int mf = 0; mf < 4; ++mf) {
#pragma unroll
        for (int r = 0; r < 4; ++r) {
            const int row_l = wm * 64 + mf * 16 + lhi * 4 + r;
            const int tgt = t_s[row_l];
            const int exc = i_s[row_l];
            float pmin = INFINITY, nmax = -INFINITY;
#pragma unroll
            for (int nf = 0; nf < 4; ++nf) {
                const float v = acc[mf][nf][r];
                const bool same = (labv[nf] == tgt);
                pmin = fminf(pmin, (same && (jv[nf] != exc)) ? v : INFINITY);
                nmax = fmaxf(nmax, same ? -INFINITY : v);
            }
#pragma unroll
            for (int s = 1; s < 16; s <<= 1) {
                pmin = fminf(pmin, __shfl_xor(pmin, s, 64));
                nmax = fmaxf(nmax, __shfl_xor(nmax, s, 64));
            }
            if (l15 == 0) {
                const int row_g = mtile * BM + row_l;
                pos_part[(size_t)row_g * NPART + ntile * 2 + wn] = pmin;
                neg_part[(size_t)row_g * NPART + ntile * 2 + wn] = nmax;
            }
        }
    }
}

// ---- per-row reduce of partials -> hinge loss -> mean (atomic) ----
__global__ __launch_bounds__(256) void rowred_kernel(const float* __restrict__ pos_part,
                                                     const float* __restrict__ neg_part,
                                                     float* __restrict__ out) {
    const int row = blockIdx.x;
    const int t = threadIdx.x;
    const float* pp = pos_part + (size_t)row * NPART;
    const float* nn = neg_part + (size_t)row * NPART;
    float p = fminf(pp[t], pp[t + 256]);
    float nx = fmaxf(nn[t], nn[t + 256]);
#pragma unroll
    for (int s = 1; s < 64; s <<= 1) {
        p = fminf(p, __shfl_xor(p, s, 64));
        nx = fmaxf(nx, __shfl_xor(nx, s, 64));
    }
    __shared__ float sp[4], sn[4];
    if ((t & 63) == 0) { sp[t >> 6] = p; sn[t >> 6] = nx; }
    __syncthreads();
    if (t == 0) {
        p = fminf(fminf(sp[0], sp[1]), fminf(sp[2], sp[3]));
        nx = fmaxf(fmaxf(sn[0], sn[1]), fmaxf(sn[2], sn[3]));
        const float l = nx - p + MARGIN;
        atomicAdd(out, (l > 0.f ? l : 0.f) * (1.0f / (float)M));
    }
}

extern "C" void kernel_launch(void* const* d_in, const int* in_sizes, int n_in,
                              void* d_out, int out_size, void* d_ws, size_t ws_size,
                              hipStream_t stream) {
    const float* inputs = (const float*)d_in[0];     // [1024,512] f32
    const float* features = (const float*)d_in[1];   // [32768,512] f32
    const int* targets = (const int*)d_in[2];        // [1024] i32
    const int* idxv = (const int*)d_in[3];           // [1024] i32
    const int* labels = (const int*)d_in[4];         // [32768] i32

    char* ws = (char*)d_ws;
    ushort_t* A = (ushort_t*)ws;                               // 1 MB
    ushort_t* B = (ushort_t*)(ws + (1u << 20));                // 32 MB
    float* pos_part = (float*)(ws + (1u << 20) + (32u << 20)); // 2 MB
    float* neg_part = pos_part + (size_t)M * NPART;            // 2 MB

    // zero the scalar accumulator
    hipMemsetAsync(d_out, 0, sizeof(float), stream);

    // f32 -> bf16 (both tensors, one grid-stride kernel)
    cvt_kernel<<<2048, 256, 0, stream>>>(inputs, A, M * K / 8, features, B, NG * K / 8);

    // fused GEMM + masked partial min/max
    gemm_kernel<<<(M / BM) * (NG / BN), 256, 0, stream>>>(A, B, targets, idxv, labels,
                                                          pos_part, neg_part);

    // per-row reduction + mean
    rowred_kernel<<<M, 256, 0, stream>>>(pos_part, neg_part, (float*)d_out);
}

// Round 3
// 176.283 us; speedup vs baseline: 1.1085x; 1.1085x over previous
//
#include <hip/hip_runtime.h>
#include <stdint.h>

#define MARGIN 0.3f
#define M 1024
#define NG 32768
#define K 512
#define BM 256
#define BN 256
#define BK 64
#define KT (K / BK)       // 8 k-tiles
#define NTILES (NG / BN)  // 128 n-tiles
#define MTILES (M / BM)   // 4 m-tiles
#define NPART (NTILES * 4)  // 512 partials per row (4 wn-stripes per ntile)

typedef __attribute__((ext_vector_type(8))) __bf16 bf16x8;
typedef __attribute__((ext_vector_type(4))) float f32x4;
typedef unsigned short ushort_t;
typedef unsigned int uint_t;

#define BAR() __builtin_amdgcn_s_barrier()
#define LGKM0() asm volatile("s_waitcnt lgkmcnt(0)" ::: "memory")

// ---- f32 -> bf16 (RNE) ----
static __device__ __forceinline__ ushort_t f2bf(float f) {
    uint_t u = __float_as_uint(f);
    u += 0x7FFFu + ((u >> 16) & 1u);
    return (ushort_t)(u >> 16);
}

__global__ __launch_bounds__(256) void cvt_kernel(const float* __restrict__ src,
                                                  ushort_t* __restrict__ dst, int n8) {
    int i = blockIdx.x * 256 + threadIdx.x;
    if (i >= n8) return;
    const float4* s4 = (const float4*)src;
    float4 a = s4[2 * i];
    float4 b = s4[2 * i + 1];
    uint4 o;
    o.x = (uint_t)f2bf(a.x) | ((uint_t)f2bf(a.y) << 16);
    o.y = (uint_t)f2bf(a.z) | ((uint_t)f2bf(a.w) << 16);
    o.z = (uint_t)f2bf(b.x) | ((uint_t)f2bf(b.y) << 16);
    o.w = (uint_t)f2bf(b.z) | ((uint_t)f2bf(b.w) << 16);
    ((uint4*)dst)[i] = o;
}

// ---- async global->LDS, 16B per lane (dest = wave-uniform base + lane*16) ----
static __device__ __forceinline__ void gload_lds16(const void* gptr, void* lptr) {
    __builtin_amdgcn_global_load_lds(
        (const __attribute__((address_space(1))) uint32_t*)(gptr),
        (__attribute__((address_space(3))) uint32_t*)(uintptr_t)(lptr),
        16, 0, 0);
}

// ---- fused 256x256 8-phase GEMM + masked min/max partial reduction ----
__global__ __launch_bounds__(512, 2) void gemm_kernel(
    const ushort_t* __restrict__ A,   // [1024][512] bf16
    const ushort_t* __restrict__ B,   // [32768][512] bf16
    const int* __restrict__ targets,  // [1024]
    const int* __restrict__ idxv,     // [1024]
    const int* __restrict__ labels,   // [32768]
    float* __restrict__ pos_part,     // [1024][NPART]
    float* __restrict__ neg_part) {   // [1024][NPART]

    // per buffer: A tile [256][64] (32KB) + B tile [256][64] (32KB); 2 buffers = 128KB
    __shared__ __align__(16) ushort_t sA[2][BM * BK];
    __shared__ __align__(16) ushort_t sB[2][BN * BK];
    __shared__ int t_s[BM];
    __shared__ int i_s[BM];
    __shared__ int l_s[BN];

    const int tid = threadIdx.x;
    const int lane = tid & 63;
    const int w = tid >> 6;    // wave 0..7
    const int wm = w >> 2;     // 0..1  (row half: 128 rows)
    const int wn = w & 3;      // 0..3  (col quarter: 64 cols)
    const int l15 = lane & 15;
    const int lhi = lane >> 4;  // 0..3
    const int bid = blockIdx.x;
    // XCD colocation: same-ntile blocks are 128 apart -> same (bid mod 8) -> same XCD
    const int ntile = bid & (NTILES - 1);
    const int mtile = bid >> 7;

    if (tid < BM) {
        t_s[tid] = targets[mtile * BM + tid];
        i_s[tid] = idxv[mtile * BM + tid];
    } else {
        l_s[tid - BM] = labels[ntile * BN + (tid - BM)];
    }

    f32x4 zero = {0.f, 0.f, 0.f, 0.f};
    f32x4 acc[8][4];
#pragma unroll
    for (int a = 0; a < 8; ++a)
#pragma unroll
        for (int b = 0; b < 4; ++b) acc[a][b] = zero;

    // staging geometry: half-tile = 128 rows x 64 cols = 16KB = 2 rounds x (512 thr x 16B)
    // LDS dest is LINEAR (rule #21); global source col-chunk is inverse-swizzled:
    // LDS chunk u' (=tid&7) of row r holds global chunk u = u' ^ (r&7), r&7 = (tid>>3)&7.
    const int rstage = tid >> 3;                              // 0..63 (row within round)
    const int cstage = (((tid & 7) ^ (rstage & 7)) << 3);     // ushort offset in row
    const ushort_t* Abase = A + (size_t)mtile * BM * K;
    const ushort_t* Bbase = B + (size_t)ntile * BN * K;

    auto stage_half = [&](const ushort_t* g, ushort_t* l) {
        gload_lds16(g + (size_t)rstage * K + cstage, l + w * 512);
        gload_lds16(g + (size_t)(64 + rstage) * K + cstage, l + 4096 + w * 512);
    };

    // swizzled fragment reads: element (r, kchunk u) lives at chunk u ^ (r&7)
    auto readA = [&](int buf, int mf, int kk) -> bf16x8 {
        const int r = wm * 128 + mf * 16 + l15;
        const int u = (kk * 4 + lhi) ^ (r & 7);
        return *(const bf16x8*)&sA[buf][r * 64 + u * 8];
    };
    auto readB = [&](int buf, int nf, int kk) -> bf16x8 {
        const int r = wn * 64 + nf * 16 + l15;
        const int u = (kk * 4 + lhi) ^ (r & 7);
        return *(const bf16x8*)&sB[buf][r * 64 + u * 8];
    };

    // ---- prologue: tile0 (A+B) + tile1 (B only); A(1) staged in kt=0's p0/p1 ----
    stage_half(Abase, &sA[0][0]);
    stage_half(Abase + (size_t)128 * K, &sA[0][8192]);
    stage_half(Bbase, &sB[0][0]);
    stage_half(Bbase + (size_t)128 * K, &sB[0][8192]);
    stage_half(Bbase + BK, &sB[1][0]);
    stage_half(Bbase + BK + (size_t)128 * K, &sB[1][8192]);
    asm volatile("s_waitcnt vmcnt(4)" ::: "memory");  // tile0's 8 loads landed; B(1) in flight
    BAR();

#pragma unroll 1
    for (int kt = 0; kt < KT; ++kt) {
        const int cur = kt & 1;
        bf16x8 av[4], bv[4];

        // ---- phase 0: kk=0, m-frags 0-3 ----
#pragma unroll
        for (int nf = 0; nf < 4; ++nf) bv[nf] = readB(cur, nf, 0);
#pragma unroll
        for (int mf = 0; mf < 4; ++mf) av[mf] = readA(cur, mf, 0);
        if (kt < KT - 1) stage_half(Abase + (size_t)(kt + 1) * BK, &sA[cur ^ 1][0]);
        BAR(); LGKM0();
        __builtin_amdgcn_s_setprio(1);
#pragma unroll
        for (int mf = 0; mf < 4; ++mf)
#pragma unroll
            for (int nf = 0; nf < 4; ++nf)
                acc[mf][nf] = __builtin_amdgcn_mfma_f32_16x16x32_bf16(av[mf], bv[nf], acc[mf][nf], 0, 0, 0);
        __builtin_amdgcn_s_setprio(0);
        BAR();

        // ---- phase 1: kk=0, m-frags 4-7 ----
#pragma unroll
        for (int mf = 0; mf < 4; ++mf) av[mf] = readA(cur, mf + 4, 0);
        if (kt < KT - 1)
            stage_half(Abase + (size_t)(kt + 1) * BK + (size_t)128 * K, &sA[cur ^ 1][8192]);
        BAR(); LGKM0();
        __builtin_amdgcn_s_setprio(1);
#pragma unroll
        for (int mf = 0; mf < 4; ++mf)
#pragma unroll
            for (int nf = 0; nf < 4; ++nf)
                acc[mf + 4][nf] = __builtin_amdgcn_mfma_f32_16x16x32_bf16(av[mf], bv[nf], acc[mf + 4][nf], 0, 0, 0);
        __builtin_amdgcn_s_setprio(0);
        BAR();

        // ---- phase 2: kk=1, m-frags 0-3 (last B reads of this tile) ----
#pragma unroll
        for (int nf = 0; nf < 4; ++nf) bv[nf] = readB(cur, nf, 1);
#pragma unroll
        for (int mf = 0; mf < 4; ++mf) av[mf] = readA(cur, mf, 1);
        BAR(); LGKM0();
        __builtin_amdgcn_s_setprio(1);
#pragma unroll
        for (int mf = 0; mf < 4; ++mf)
#pragma unroll
            for (int nf = 0; nf < 4; ++nf)
                acc[mf][nf] = __builtin_amdgcn_mfma_f32_16x16x32_bf16(av[mf], bv[nf], acc[mf][nf], 0, 0, 0);
        __builtin_amdgcn_s_setprio(0);
        BAR();

        // ---- phase 3: kk=1, m-frags 4-7; stage B(kt+2); counted vmcnt ----
#pragma unroll
        for (int mf = 0; mf < 4; ++mf) av[mf] = readA(cur, mf + 4, 1);
        if (kt < KT - 2) {
            stage_half(Bbase + (size_t)(kt + 2) * BK, &sB[cur][0]);
            stage_half(Bbase + (size_t)(kt + 2) * BK + (size_t)128 * K, &sB[cur][8192]);
            // leave the 4 B(kt+2) loads in flight; A(kt+1)+older must have landed
            asm volatile("s_waitcnt vmcnt(4)" ::: "memory");
        } else {
            asm volatile("s_waitcnt vmcnt(0)" ::: "memory");
        }
        BAR(); LGKM0();
        __builtin_amdgcn_s_setprio(1);
#pragma unroll
        for (int mf = 0; mf < 4; ++mf)
#pragma unroll
            for (int nf = 0; nf < 4; ++nf)
                acc[mf + 4][nf] = __builtin_amdgcn_mfma_f32_16x16x32_bf16(av[mf], bv[nf], acc[mf + 4][nf], 0, 0, 0);
        __builtin_amdgcn_s_setprio(0);
        BAR();
    }

    // ---- epilogue: masked min/max over this wave's 64-col stripe ----
    int labv[4], jv[4];
#pragma unroll
    for (int nf = 0; nf < 4; ++nf) {
        const int cl = wn * 64 + nf * 16 + l15;
        labv[nf] = l_s[cl];
        jv[nf] = ntile * BN + cl;
    }
#pragma unroll
    for (int mf = 0; mf < 8; ++mf) {
#pragma unroll
        for (int r = 0; r < 4; ++r) {
            const int row_l = wm * 128 + mf * 16 + lhi * 4 + r;
            const int tgt = t_s[row_l];
            const int exc = i_s[row_l];
            float pmin = INFINITY, nmax = -INFINITY;
#pragma unroll
            for (int nf = 0; nf < 4; ++nf) {
                const float v = acc[mf][nf][r];
                const bool same = (labv[nf] == tgt);
                pmin = fminf(pmin, (same && (jv[nf] != exc)) ? v : INFINITY);
                nmax = fmaxf(nmax, same ? -INFINITY : v);
            }
#pragma unroll
            for (int s = 1; s < 16; s <<= 1) {
                pmin = fminf(pmin, __shfl_xor(pmin, s, 64));
                nmax = fmaxf(nmax, __shfl_xor(nmax, s, 64));
            }
            if (l15 == 0) {
                const int row_g = mtile * BM + row_l;
                pos_part[(size_t)row_g * NPART + ntile * 4 + wn] = pmin;
                neg_part[(size_t)row_g * NPART + ntile * 4 + wn] = nmax;
            }
        }
    }
}

// ---- per-row reduce of partials -> hinge loss -> mean (atomic) ----
__global__ __launch_bounds__(256) void rowred_kernel(const float* __restrict__ pos_part,
                                                     const float* __restrict__ neg_part,
                                                     float* __restrict__ out) {
    const int row = blockIdx.x;
    const int t = threadIdx.x;
    const float* pp = pos_part + (size_t)row * NPART;
    const float* nn = neg_part + (size_t)row * NPART;
    float p = fminf(pp[t], pp[t + 256]);
    float nx = fmaxf(nn[t], nn[t + 256]);
#pragma unroll
    for (int s = 1; s < 64; s <<= 1) {
        p = fminf(p, __shfl_xor(p, s, 64));
        nx = fmaxf(nx, __shfl_xor(nx, s, 64));
    }
    __shared__ float sp[4], sn[4];
    if ((t & 63) == 0) { sp[t >> 6] = p; sn[t >> 6] = nx; }
    __syncthreads();
    if (t == 0) {
        p = fminf(fminf(sp[0], sp[1]), fminf(sp[2], sp[3]));
        nx = fmaxf(fmaxf(sn[0], sn[1]), fmaxf(sn[2], sn[3]));
        const float l = nx - p + MARGIN;
        atomicAdd(out, (l > 0.f ? l : 0.f) * (1.0f / (float)M));
    }
}

extern "C" void kernel_launch(void* const* d_in, const int* in_sizes, int n_in,
                              void* d_out, int out_size, void* d_ws, size_t ws_size,
                              hipStream_t stream) {
    const float* inputs = (const float*)d_in[0];     // [1024,512] f32
    const float* features = (const float*)d_in[1];   // [32768,512] f32
    const int* targets = (const int*)d_in[2];        // [1024] i32
    const int* idxv = (const int*)d_in[3];           // [1024] i32
    const int* labels = (const int*)d_in[4];         // [32768] i32

    char* ws = (char*)d_ws;
    ushort_t* A = (ushort_t*)ws;                               // 1 MB
    ushort_t* B = (ushort_t*)(ws + (1u << 20));                // 32 MB
    float* pos_part = (float*)(ws + (1u << 20) + (32u << 20)); // 2 MB
    float* neg_part = pos_part + (size_t)M * NPART;            // 2 MB

    // zero the scalar accumulator
    hipMemsetAsync(d_out, 0, sizeof(float), stream);

    // f32 -> bf16 (exact grids, no branch)
    cvt_kernel<<<(NG * K / 8) / 256, 256, 0, stream>>>(features, B, NG * K / 8);
    cvt_kernel<<<(M * K / 8) / 256, 256, 0, stream>>>(inputs, A, M * K / 8);

    // fused 8-phase GEMM + masked partial min/max
    gemm_kernel<<<MTILES * NTILES, 512, 0, stream>>>(A, B, targets, idxv, labels,
                                                     pos_part, neg_part);

    // per-row reduction + mean
    rowred_kernel<<<M, 256, 0, stream>>>(pos_part, neg_part, (float*)d_out);
}

// Round 4
// 163.791 us; speedup vs baseline: 1.1931x; 1.0763x over previous
//
#include <hip/hip_runtime.h>
#include <stdint.h>

#define MARGIN 0.3f
#define M 1024
#define NG 32768
#define K 512
#define BM 256
#define BN 256
#define BK 64
#define KT (K / BK)       // 8 k-tiles
#define NTILES (NG / BN)  // 128 n-tiles
#define MTILES (M / BM)   // 4 m-tiles
#define NPART (NTILES * 4)  // 512 partials per row (4 wn-stripes per ntile)

typedef __attribute__((ext_vector_type(8))) __bf16 bf16x8;
typedef __attribute__((ext_vector_type(4))) float f32x4;
typedef unsigned short ushort_t;
typedef unsigned int uint_t;

#define BAR() __builtin_amdgcn_s_barrier()
#define LGKM0() asm volatile("s_waitcnt lgkmcnt(0)" ::: "memory")
#define SGB0() __builtin_amdgcn_sched_barrier(0)

// ---- f32 -> bf16 (RNE) ----
static __device__ __forceinline__ ushort_t f2bf(float f) {
    uint_t u = __float_as_uint(f);
    u += 0x7FFFu + ((u >> 16) & 1u);
    return (ushort_t)(u >> 16);
}

__global__ __launch_bounds__(256) void cvt_kernel(const float* __restrict__ src,
                                                  ushort_t* __restrict__ dst, int n8) {
    int i = blockIdx.x * 256 + threadIdx.x;
    if (i >= n8) return;
    const float4* s4 = (const float4*)src;
    float4 a = s4[2 * i];
    float4 b = s4[2 * i + 1];
    uint4 o;
    o.x = (uint_t)f2bf(a.x) | ((uint_t)f2bf(a.y) << 16);
    o.y = (uint_t)f2bf(a.z) | ((uint_t)f2bf(a.w) << 16);
    o.z = (uint_t)f2bf(b.x) | ((uint_t)f2bf(b.y) << 16);
    o.w = (uint_t)f2bf(b.z) | ((uint_t)f2bf(b.w) << 16);
    ((uint4*)dst)[i] = o;
}

// ---- async global->LDS, 16B per lane (dest = wave-uniform base + lane*16) ----
static __device__ __forceinline__ void gload_lds16(const void* gptr, void* lptr) {
    __builtin_amdgcn_global_load_lds(
        (const __attribute__((address_space(1))) uint32_t*)(gptr),
        (__attribute__((address_space(3))) uint32_t*)(uintptr_t)(lptr),
        16, 0, 0);
}

// ---- alias-opaque LDS fragment read: compiler cannot connect this to the
// async global_load_lds writes, so it inserts NO vmcnt waits for it.
// Ordering vs staging is enforced manually (BAR / LGKM0 / counted vmcnt).
static __device__ __forceinline__ bf16x8 lds_read_b128(const ushort_t* p) {
    bf16x8 r;
    asm volatile("ds_read_b128 %0, %1"
                 : "=v"(r)
                 : "v"((const __attribute__((address_space(3))) ushort_t*)p));
    return r;
}

// ---- fused 256x256 8-phase GEMM + masked min/max partial reduction ----
__global__ __launch_bounds__(512, 2) void gemm_kernel(
    const ushort_t* __restrict__ A,   // [1024][512] bf16
    const ushort_t* __restrict__ B,   // [32768][512] bf16
    const int* __restrict__ targets,  // [1024]
    const int* __restrict__ idxv,     // [1024]
    const int* __restrict__ labels,   // [32768]
    float* __restrict__ pos_part,     // [1024][NPART]
    float* __restrict__ neg_part) {   // [1024][NPART]

    __shared__ __align__(16) ushort_t sA[2][BM * BK];
    __shared__ __align__(16) ushort_t sB[2][BN * BK];
    __shared__ int t_s[BM];
    __shared__ int i_s[BM];
    __shared__ int l_s[BN];

    const int tid = threadIdx.x;
    const int lane = tid & 63;
    const int w = tid >> 6;    // wave 0..7
    const int wm = w >> 2;     // 0..1  (row half: 128 rows)
    const int wn = w & 3;      // 0..3  (col quarter: 64 cols)
    const int l15 = lane & 15;
    const int lhi = lane >> 4;  // 0..3
    const int bid = blockIdx.x;
    // XCD colocation: same-ntile blocks are 128 apart -> same (bid mod 8) -> same XCD
    const int ntile = bid & (NTILES - 1);
    const int mtile = bid >> 7;

    if (tid < BM) {
        t_s[tid] = targets[mtile * BM + tid];
        i_s[tid] = idxv[mtile * BM + tid];
    } else {
        l_s[tid - BM] = labels[ntile * BN + (tid - BM)];
    }

    f32x4 zero = {0.f, 0.f, 0.f, 0.f};
    f32x4 acc[8][4];
#pragma unroll
    for (int a = 0; a < 8; ++a)
#pragma unroll
        for (int b = 0; b < 4; ++b) acc[a][b] = zero;

    // staging: LDS dest LINEAR; global source col-chunk inverse-XOR-swizzled
    const int rstage = tid >> 3;                              // 0..63
    const int cstage = (((tid & 7) ^ (rstage & 7)) << 3);     // ushort offset in row
    const ushort_t* Abase = A + (size_t)mtile * BM * K;
    const ushort_t* Bbase = B + (size_t)ntile * BN * K;

    auto stage_half = [&](const ushort_t* g, ushort_t* l) {
        gload_lds16(g + (size_t)rstage * K + cstage, l + w * 512);
        gload_lds16(g + (size_t)(64 + rstage) * K + cstage, l + 4096 + w * 512);
    };

    // swizzled fragment reads (asm): element (r, kchunk u) lives at chunk u ^ (r&7)
    auto readA = [&](int buf, int mf, int kk) -> bf16x8 {
        const int r = wm * 128 + mf * 16 + l15;
        const int u = (kk * 4 + lhi) ^ (r & 7);
        return lds_read_b128(&sA[buf][r * 64 + u * 8]);
    };
    auto readB = [&](int buf, int nf, int kk) -> bf16x8 {
        const int r = wn * 64 + nf * 16 + l15;
        const int u = (kk * 4 + lhi) ^ (r & 7);
        return lds_read_b128(&sB[buf][r * 64 + u * 8]);
    };

    // ---- prologue: tile0 (A+B) + tile1 (B only) ----
    stage_half(Abase, &sA[0][0]);
    stage_half(Abase + (size_t)128 * K, &sA[0][8192]);
    stage_half(Bbase, &sB[0][0]);
    stage_half(Bbase + (size_t)128 * K, &sB[0][8192]);
    stage_half(Bbase + BK, &sB[1][0]);
    stage_half(Bbase + BK + (size_t)128 * K, &sB[1][8192]);
    asm volatile("s_waitcnt vmcnt(4)" ::: "memory");  // tile0 landed; B(1) in flight
    BAR();

#pragma unroll 1
    for (int kt = 0; kt < KT; ++kt) {
        const int cur = kt & 1;
        bf16x8 av[4], bv[4];

        // ---- phase 0: kk=0, m-frags 0-3 ----
#pragma unroll
        for (int nf = 0; nf < 4; ++nf) bv[nf] = readB(cur, nf, 0);
#pragma unroll
        for (int mf = 0; mf < 4; ++mf) av[mf] = readA(cur, mf, 0);
        if (kt < KT - 1) stage_half(Abase + (size_t)(kt + 1) * BK, &sA[cur ^ 1][0]);
        BAR(); LGKM0(); SGB0();
        __builtin_amdgcn_s_setprio(1);
#pragma unroll
        for (int mf = 0; mf < 4; ++mf)
#pragma unroll
            for (int nf = 0; nf < 4; ++nf)
                acc[mf][nf] = __builtin_amdgcn_mfma_f32_16x16x32_bf16(av[mf], bv[nf], acc[mf][nf], 0, 0, 0);
        __builtin_amdgcn_s_setprio(0);
        BAR();

        // ---- phase 1: kk=0, m-frags 4-7 ----
#pragma unroll
        for (int mf = 0; mf < 4; ++mf) av[mf] = readA(cur, mf + 4, 0);
        if (kt < KT - 1)
            stage_half(Abase + (size_t)(kt + 1) * BK + (size_t)128 * K, &sA[cur ^ 1][8192]);
        BAR(); LGKM0(); SGB0();
        __builtin_amdgcn_s_setprio(1);
#pragma unroll
        for (int mf = 0; mf < 4; ++mf)
#pragma unroll
            for (int nf = 0; nf < 4; ++nf)
                acc[mf + 4][nf] = __builtin_amdgcn_mfma_f32_16x16x32_bf16(av[mf], bv[nf], acc[mf + 4][nf], 0, 0, 0);
        __builtin_amdgcn_s_setprio(0);
        BAR();

        // ---- phase 2: kk=1, m-frags 0-3 (last reads of sB[cur] this tile) ----
#pragma unroll
        for (int nf = 0; nf < 4; ++nf) bv[nf] = readB(cur, nf, 1);
#pragma unroll
        for (int mf = 0; mf < 4; ++mf) av[mf] = readA(cur, mf, 1);
        BAR(); LGKM0(); SGB0();
        __builtin_amdgcn_s_setprio(1);
#pragma unroll
        for (int mf = 0; mf < 4; ++mf)
#pragma unroll
            for (int nf = 0; nf < 4; ++nf)
                acc[mf][nf] = __builtin_amdgcn_mfma_f32_16x16x32_bf16(av[mf], bv[nf], acc[mf][nf], 0, 0, 0);
        __builtin_amdgcn_s_setprio(0);
        BAR();

        // ---- phase 3: kk=1, m-frags 4-7; stage B(kt+2); counted vmcnt ----
#pragma unroll
        for (int mf = 0; mf < 4; ++mf) av[mf] = readA(cur, mf + 4, 1);
        if (kt < KT - 2) {
            stage_half(Bbase + (size_t)(kt + 2) * BK, &sB[cur][0]);
            stage_half(Bbase + (size_t)(kt + 2) * BK + (size_t)128 * K, &sB[cur][8192]);
            // wait: A(kt+1)+B(kt+1) landed; leave B(kt+2)'s 4 loads in flight
            asm volatile("s_waitcnt vmcnt(4)" ::: "memory");
        } else {
            asm volatile("s_waitcnt vmcnt(0)" ::: "memory");
        }
        BAR(); LGKM0(); SGB0();
        __builtin_amdgcn_s_setprio(1);
#pragma unroll
        for (int mf = 0; mf < 4; ++mf)
#pragma unroll
            for (int nf = 0; nf < 4; ++nf)
                acc[mf + 4][nf] = __builtin_amdgcn_mfma_f32_16x16x32_bf16(av[mf], bv[nf], acc[mf + 4][nf], 0, 0, 0);
        __builtin_amdgcn_s_setprio(0);
        BAR();
    }

    // ---- epilogue: masked min/max over this wave's 64-col stripe ----
    int labv[4], jv[4];
#pragma unroll
    for (int nf = 0; nf < 4; ++nf) {
        const int cl = wn * 64 + nf * 16 + l15;
        labv[nf] = l_s[cl];
        jv[nf] = ntile * BN + cl;
    }
#pragma unroll
    for (int mf = 0; mf < 8; ++mf) {
#pragma unroll
        for (int r = 0; r < 4; ++r) {
            const int row_l = wm * 128 + mf * 16 + lhi * 4 + r;
            const int tgt = t_s[row_l];
            const int exc = i_s[row_l];
            float pmin = INFINITY, nmax = -INFINITY;
#pragma unroll
            for (int nf = 0; nf < 4; ++nf) {
                const float v = acc[mf][nf][r];
                const bool same = (labv[nf] == tgt);
                pmin = fminf(pmin, (same && (jv[nf] != exc)) ? v : INFINITY);
                nmax = fmaxf(nmax, same ? -INFINITY : v);
            }
#pragma unroll
            for (int s = 1; s < 16; s <<= 1) {
                pmin = fminf(pmin, __shfl_xor(pmin, s, 64));
                nmax = fmaxf(nmax, __shfl_xor(nmax, s, 64));
            }
            if (l15 == 0) {
                const int row_g = mtile * BM + row_l;
                pos_part[(size_t)row_g * NPART + ntile * 4 + wn] = pmin;
                neg_part[(size_t)row_g * NPART + ntile * 4 + wn] = nmax;
            }
        }
    }
}

// ---- per-row reduce of partials -> hinge loss ----
__global__ __launch_bounds__(256) void rowred_kernel(const float* __restrict__ pos_part,
                                                     const float* __restrict__ neg_part,
                                                     float* __restrict__ loss) {
    const int row = blockIdx.x;
    const int t = threadIdx.x;
    const float* pp = pos_part + (size_t)row * NPART;
    const float* nn = neg_part + (size_t)row * NPART;
    float p = fminf(pp[t], pp[t + 256]);
    float nx = fmaxf(nn[t], nn[t + 256]);
#pragma unroll
    for (int s = 1; s < 64; s <<= 1) {
        p = fminf(p, __shfl_xor(p, s, 64));
        nx = fmaxf(nx, __shfl_xor(nx, s, 64));
    }
    __shared__ float sp[4], sn[4];
    if ((t & 63) == 0) { sp[t >> 6] = p; sn[t >> 6] = nx; }
    __syncthreads();
    if (t == 0) {
        p = fminf(fminf(sp[0], sp[1]), fminf(sp[2], sp[3]));
        nx = fmaxf(fmaxf(sn[0], sn[1]), fmaxf(sn[2], sn[3]));
        const float l = nx - p + MARGIN;
        loss[row] = l > 0.f ? l : 0.f;
    }
}

// ---- mean over 1024 losses -> scalar ----
__global__ __launch_bounds__(256) void final_kernel(const float* __restrict__ loss,
                                                    float* __restrict__ out) {
    const int t = threadIdx.x;
    float s = loss[t] + loss[t + 256] + loss[t + 512] + loss[t + 768];
#pragma unroll
    for (int sh = 1; sh < 64; sh <<= 1) s += __shfl_xor(s, sh, 64);
    __shared__ float sb[4];
    if ((t & 63) == 0) sb[t >> 6] = s;
    __syncthreads();
    if (t == 0) out[0] = (sb[0] + sb[1] + sb[2] + sb[3]) * (1.0f / 1024.0f);
}

extern "C" void kernel_launch(void* const* d_in, const int* in_sizes, int n_in,
                              void* d_out, int out_size, void* d_ws, size_t ws_size,
                              hipStream_t stream) {
    const float* inputs = (const float*)d_in[0];     // [1024,512] f32
    const float* features = (const float*)d_in[1];   // [32768,512] f32
    const int* targets = (const int*)d_in[2];        // [1024] i32
    const int* idxv = (const int*)d_in[3];           // [1024] i32
    const int* labels = (const int*)d_in[4];         // [32768] i32

    char* ws = (char*)d_ws;
    ushort_t* A = (ushort_t*)ws;                               // 1 MB
    ushort_t* B = (ushort_t*)(ws + (1u << 20));                // 32 MB
    float* pos_part = (float*)(ws + (1u << 20) + (32u << 20)); // 2 MB
    float* neg_part = pos_part + (size_t)M * NPART;            // 2 MB
    float* loss = neg_part + (size_t)M * NPART;                // 4 KB

    // f32 -> bf16 (exact grids)
    cvt_kernel<<<(NG * K / 8) / 256, 256, 0, stream>>>(features, B, NG * K / 8);
    cvt_kernel<<<(M * K / 8) / 256, 256, 0, stream>>>(inputs, A, M * K / 8);

    // fused 8-phase GEMM + masked partial min/max
    gemm_kernel<<<MTILES * NTILES, 512, 0, stream>>>(A, B, targets, idxv, labels,
                                                     pos_part, neg_part);

    // per-row reduction + mean
    rowred_kernel<<<M, 256, 0, stream>>>(pos_part, neg_part, loss);
    final_kernel<<<1, 256, 0, stream>>>(loss, (float*)d_out);
}

// Round 5
// 152.050 us; speedup vs baseline: 1.2852x; 1.0772x over previous
//
#include <hip/hip_runtime.h>
#include <stdint.h>

#define MARGIN 0.3f
#define M 1024
#define NG 32768
#define K 512
#define BM 256
#define BN 256
#define BK 64
#define KT (K / BK)       // 8 k-tiles
#define NTILES (NG / BN)  // 128 n-tiles
#define MTILES (M / BM)   // 4 m-tiles
#define NPART (NTILES * 4)  // 512 partials per row

typedef __attribute__((ext_vector_type(8))) __bf16 bf16x8;
typedef __attribute__((ext_vector_type(4))) float f32x4;
typedef unsigned short ushort_t;
typedef unsigned int uint_t;

#define BAR() __builtin_amdgcn_s_barrier()
#define SGB0() __builtin_amdgcn_sched_barrier(0)
#define WAIT_LGKM(n) asm volatile("s_waitcnt lgkmcnt(" #n ")" ::: "memory")
#define WAIT_VM0() asm volatile("s_waitcnt vmcnt(0)" ::: "memory")

// ---- f32 -> bf16 (RNE) ----
static __device__ __forceinline__ ushort_t f2bf(float f) {
    uint_t u = __float_as_uint(f);
    u += 0x7FFFu + ((u >> 16) & 1u);
    return (ushort_t)(u >> 16);
}

__global__ __launch_bounds__(256) void cvt_kernel(const float* __restrict__ src,
                                                  ushort_t* __restrict__ dst, int n8) {
    int i = blockIdx.x * 256 + threadIdx.x;
    if (i >= n8) return;
    const float4* s4 = (const float4*)src;
    float4 a = s4[2 * i];
    float4 b = s4[2 * i + 1];
    uint4 o;
    o.x = (uint_t)f2bf(a.x) | ((uint_t)f2bf(a.y) << 16);
    o.y = (uint_t)f2bf(a.z) | ((uint_t)f2bf(a.w) << 16);
    o.z = (uint_t)f2bf(b.x) | ((uint_t)f2bf(b.y) << 16);
    o.w = (uint_t)f2bf(b.z) | ((uint_t)f2bf(b.w) << 16);
    ((uint4*)dst)[i] = o;
}

// ---- async global->LDS, 16B per lane ----
static __device__ __forceinline__ void gload_lds16(const void* gptr, void* lptr) {
    __builtin_amdgcn_global_load_lds(
        (const __attribute__((address_space(1))) uint32_t*)(gptr),
        (__attribute__((address_space(3))) uint32_t*)(uintptr_t)(lptr),
        16, 0, 0);
}

// ---- asm LDS read: lgkmcnt accounting is OURS (counted waits below) ----
static __device__ __forceinline__ bf16x8 lds_read_b128(const ushort_t* p) {
    bf16x8 r;
    asm volatile("ds_read_b128 %0, %1"
                 : "=v"(r)
                 : "v"((const __attribute__((address_space(3))) ushort_t*)p));
    return r;
}

// ---- DPP lane-group-of-16 reduction helper (pure VALU, no LDS traffic) ----
template <int CTRL>
static __device__ __forceinline__ float dpp_mv(float x) {
    return __int_as_float(__builtin_amdgcn_update_dpp(
        0, __float_as_int(x), CTRL, 0xF, 0xF, true));
}
static __device__ __forceinline__ float red16_min(float x) {
    x = fminf(x, dpp_mv<0xB1>(x));   // quad_perm(1,0,3,2)  ~ xor1
    x = fminf(x, dpp_mv<0x4E>(x));   // quad_perm(2,3,0,1)  ~ xor2
    x = fminf(x, dpp_mv<0x141>(x));  // row_half_mirror     ~ xor4 (post-reduce)
    x = fminf(x, dpp_mv<0x140>(x));  // row_mirror          ~ xor8 (post-reduce)
    return x;
}
static __device__ __forceinline__ float red16_max(float x) {
    x = fmaxf(x, dpp_mv<0xB1>(x));
    x = fmaxf(x, dpp_mv<0x4E>(x));
    x = fmaxf(x, dpp_mv<0x141>(x));
    x = fmaxf(x, dpp_mv<0x140>(x));
    return x;
}

// ---- fused 256x256 GEMM, 1 barrier/kt, counted-lgkm MFMA/LDS overlap ----
__global__ __launch_bounds__(512, 2) void gemm_kernel(
    const ushort_t* __restrict__ A,   // [1024][512] bf16
    const ushort_t* __restrict__ B,   // [32768][512] bf16
    const int* __restrict__ targets,  // [1024]
    const int* __restrict__ idxv,     // [1024]
    const int* __restrict__ labels,   // [32768]
    float* __restrict__ pos_part,     // [1024][NPART]
    float* __restrict__ neg_part) {   // [1024][NPART]

    __shared__ __align__(16) ushort_t sA[2][BM * BK];
    __shared__ __align__(16) ushort_t sB[2][BN * BK];
    __shared__ int t_s[BM];
    __shared__ int i_s[BM];
    __shared__ int l_s[BN];

    const int tid = threadIdx.x;
    const int lane = tid & 63;
    const int w = tid >> 6;    // wave 0..7
    const int wm = w >> 2;     // 0..1
    const int wn = w & 3;      // 0..3
    const int l15 = lane & 15;
    const int lhi = lane >> 4;  // 0..3
    const int bid = blockIdx.x;
    const int ntile = bid & (NTILES - 1);  // same-ntile blocks -> same XCD
    const int mtile = bid >> 7;

    if (tid < BM) {
        t_s[tid] = targets[mtile * BM + tid];
        i_s[tid] = idxv[mtile * BM + tid];
    } else {
        l_s[tid - BM] = labels[ntile * BN + (tid - BM)];
    }

    f32x4 zero = {0.f, 0.f, 0.f, 0.f};
    f32x4 acc[8][4];
#pragma unroll
    for (int a = 0; a < 8; ++a)
#pragma unroll
        for (int b = 0; b < 4; ++b) acc[a][b] = zero;

    // staging: LDS dest LINEAR; global source col-chunk inverse-XOR-swizzled
    const int rstage = tid >> 3;
    const int cstage = (((tid & 7) ^ (rstage & 7)) << 3);
    const ushort_t* Abase = A + (size_t)mtile * BM * K;
    const ushort_t* Bbase = B + (size_t)ntile * BN * K;

    auto stage_half = [&](const ushort_t* g, ushort_t* l) {
        gload_lds16(g + (size_t)rstage * K + cstage, l + w * 512);
        gload_lds16(g + (size_t)(64 + rstage) * K + cstage, l + 4096 + w * 512);
    };
    auto stage_tile = [&](int buf, int kt) {  // A(kt)+B(kt) -> buffers[buf], 8 gloads
        stage_half(Abase + (size_t)kt * BK, &sA[buf][0]);
        stage_half(Abase + (size_t)kt * BK + (size_t)128 * K, &sA[buf][8192]);
        stage_half(Bbase + (size_t)kt * BK, &sB[buf][0]);
        stage_half(Bbase + (size_t)kt * BK + (size_t)128 * K, &sB[buf][8192]);
    };

    // swizzled fragment read addresses: element (r, kchunk u) at chunk u ^ (r&7)
    auto readA = [&](int buf, int mf, int kk) -> bf16x8 {
        const int r = wm * 128 + mf * 16 + l15;
        const int u = (kk * 4 + lhi) ^ (r & 7);
        return lds_read_b128(&sA[buf][r * 64 + u * 8]);
    };
    auto readB = [&](int buf, int nf, int kk) -> bf16x8 {
        const int r = wn * 64 + nf * 16 + l15;
        const int u = (kk * 4 + lhi) ^ (r & 7);
        return lds_read_b128(&sB[buf][r * 64 + u * 8]);
    };

    // ---- prologue: tile0 -> buffers[0] ----
    stage_tile(0, 0);
    WAIT_VM0();
    BAR();

#pragma unroll 1
    for (int kt = 0; kt < KT; ++kt) {
        const int cur = kt & 1;
        bf16x8 b0[4], a0lo[4], a0hi[4], b1[4], a1lo[4], a1hi[4];

        // issue reads 0-15: b0, a0lo, a0hi, b1   (asm order = retire order)
#pragma unroll
        for (int nf = 0; nf < 4; ++nf) b0[nf] = readB(cur, nf, 0);
#pragma unroll
        for (int mf = 0; mf < 4; ++mf) a0lo[mf] = readA(cur, mf, 0);
#pragma unroll
        for (int mf = 0; mf < 4; ++mf) a0hi[mf] = readA(cur, mf + 4, 0);
#pragma unroll
        for (int nf = 0; nf < 4; ++nf) b1[nf] = readB(cur, nf, 1);

        // stage next tile into [cur^1] (safe: end-of-(kt-1) barrier cleared readers)
        if (kt + 1 < KT) stage_tile(cur ^ 1, kt + 1);

        WAIT_LGKM(8); SGB0();   // b0 + a0lo retired
        __builtin_amdgcn_s_setprio(1);
#pragma unroll
        for (int mf = 0; mf < 4; ++mf)
#pragma unroll
            for (int nf = 0; nf < 4; ++nf)
                acc[mf][nf] = __builtin_amdgcn_mfma_f32_16x16x32_bf16(a0lo[mf], b0[nf], acc[mf][nf], 0, 0, 0);
        __builtin_amdgcn_s_setprio(0);
        SGB0();

#pragma unroll
        for (int mf = 0; mf < 4; ++mf) a1lo[mf] = readA(cur, mf, 1);  // reads 16-19

        WAIT_LGKM(8); SGB0();   // a0hi retired (outstanding: b1 + a1lo)
        __builtin_amdgcn_s_setprio(1);
#pragma unroll
        for (int mf = 0; mf < 4; ++mf)
#pragma unroll
            for (int nf = 0; nf < 4; ++nf)
                acc[mf + 4][nf] = __builtin_amdgcn_mfma_f32_16x16x32_bf16(a0hi[mf], b0[nf], acc[mf + 4][nf], 0, 0, 0);
        __builtin_amdgcn_s_setprio(0);
        SGB0();

#pragma unroll
        for (int mf = 0; mf < 4; ++mf) a1hi[mf] = readA(cur, mf + 4, 1);  // reads 20-23

        WAIT_LGKM(4); SGB0();   // b1 + a1lo retired (outstanding: a1hi)
        __builtin_amdgcn_s_setprio(1);
#pragma unroll
        for (int mf = 0; mf < 4; ++mf)
#pragma unroll
            for (int nf = 0; nf < 4; ++nf)
                acc[mf][nf] = __builtin_amdgcn_mfma_f32_16x16x32_bf16(a1lo[mf], b1[nf], acc[mf][nf], 0, 0, 0);
        __builtin_amdgcn_s_setprio(0);
        SGB0();

        WAIT_LGKM(0); SGB0();   // a1hi retired
        __builtin_amdgcn_s_setprio(1);
#pragma unroll
        for (int mf = 0; mf < 4; ++mf)
#pragma unroll
            for (int nf = 0; nf < 4; ++nf)
                acc[mf + 4][nf] = __builtin_amdgcn_mfma_f32_16x16x32_bf16(a1hi[mf], b1[nf], acc[mf + 4][nf], 0, 0, 0);
        __builtin_amdgcn_s_setprio(0);
        SGB0();

        WAIT_VM0();   // next tile landed (issued ~a full kt ago -> near-free)
        BAR();        // all waves done reading [cur]; [cur^1] ready
    }

    // ---- epilogue: masked min/max, DPP 16-lane reduce (no LDS traffic) ----
    int labv[4], jv[4];
#pragma unroll
    for (int nf = 0; nf < 4; ++nf) {
        const int cl = wn * 64 + nf * 16 + l15;
        labv[nf] = l_s[cl];
        jv[nf] = ntile * BN + cl;
    }
#pragma unroll
    for (int mf = 0; mf < 8; ++mf) {
#pragma unroll
        for (int r = 0; r < 4; ++r) {
            const int row_l = wm * 128 + mf * 16 + lhi * 4 + r;
            const int tgt = t_s[row_l];
            const int exc = i_s[row_l];
            float pmin = INFINITY, nmax = -INFINITY;
#pragma unroll
            for (int nf = 0; nf < 4; ++nf) {
                const float v = acc[mf][nf][r];
                const bool same = (labv[nf] == tgt);
                pmin = fminf(pmin, (same && (jv[nf] != exc)) ? v : INFINITY);
                nmax = fmaxf(nmax, same ? -INFINITY : v);
            }
            pmin = red16_min(pmin);
            nmax = red16_max(nmax);
            if (l15 == 0) {
                const int row_g = mtile * BM + row_l;
                pos_part[(size_t)row_g * NPART + ntile * 4 + wn] = pmin;
                neg_part[(size_t)row_g * NPART + ntile * 4 + wn] = nmax;
            }
        }
    }
}

// ---- per-row reduce of partials -> hinge loss ----
__global__ __launch_bounds__(256) void rowred_kernel(const float* __restrict__ pos_part,
                                                     const float* __restrict__ neg_part,
                                                     float* __restrict__ loss) {
    const int row = blockIdx.x;
    const int t = threadIdx.x;
    const float* pp = pos_part + (size_t)row * NPART;
    const float* nn = neg_part + (size_t)row * NPART;
    float p = fminf(pp[t], pp[t + 256]);
    float nx = fmaxf(nn[t], nn[t + 256]);
#pragma unroll
    for (int s = 1; s < 64; s <<= 1) {
        p = fminf(p, __shfl_xor(p, s, 64));
        nx = fmaxf(nx, __shfl_xor(nx, s, 64));
    }
    __shared__ float sp[4], sn[4];
    if ((t & 63) == 0) { sp[t >> 6] = p; sn[t >> 6] = nx; }
    __syncthreads();
    if (t == 0) {
        p = fminf(fminf(sp[0], sp[1]), fminf(sp[2], sp[3]));
        nx = fmaxf(fmaxf(sn[0], sn[1]), fmaxf(sn[2], sn[3]));
        const float l = nx - p + MARGIN;
        loss[row] = l > 0.f ? l : 0.f;
    }
}

// ---- mean over 1024 losses -> scalar ----
__global__ __launch_bounds__(256) void final_kernel(const float* __restrict__ loss,
                                                    float* __restrict__ out) {
    const int t = threadIdx.x;
    float s = loss[t] + loss[t + 256] + loss[t + 512] + loss[t + 768];
#pragma unroll
    for (int sh = 1; sh < 64; sh <<= 1) s += __shfl_xor(s, sh, 64);
    __shared__ float sb[4];
    if ((t & 63) == 0) sb[t >> 6] = s;
    __syncthreads();
    if (t == 0) out[0] = (sb[0] + sb[1] + sb[2] + sb[3]) * (1.0f / 1024.0f);
}

extern "C" void kernel_launch(void* const* d_in, const int* in_sizes, int n_in,
                              void* d_out, int out_size, void* d_ws, size_t ws_size,
                              hipStream_t stream) {
    const float* inputs = (const float*)d_in[0];     // [1024,512] f32
    const float* features = (const float*)d_in[1];   // [32768,512] f32
    const int* targets = (const int*)d_in[2];        // [1024] i32
    const int* idxv = (const int*)d_in[3];           // [1024] i32
    const int* labels = (const int*)d_in[4];         // [32768] i32

    char* ws = (char*)d_ws;
    ushort_t* A = (ushort_t*)ws;                               // 1 MB
    ushort_t* B = (ushort_t*)(ws + (1u << 20));                // 32 MB
    float* pos_part = (float*)(ws + (1u << 20) + (32u << 20)); // 2 MB
    float* neg_part = pos_part + (size_t)M * NPART;            // 2 MB
    float* loss = neg_part + (size_t)M * NPART;                // 4 KB

    // f32 -> bf16
    cvt_kernel<<<(NG * K / 8) / 256, 256, 0, stream>>>(features, B, NG * K / 8);
    cvt_kernel<<<(M * K / 8) / 256, 256, 0, stream>>>(inputs, A, M * K / 8);

    // fused GEMM + masked partial min/max
    gemm_kernel<<<MTILES * NTILES, 512, 0, stream>>>(A, B, targets, idxv, labels,
                                                     pos_part, neg_part);

    // per-row reduction + mean
    rowred_kernel<<<M, 256, 0, stream>>>(pos_part, neg_part, loss);
    final_kernel<<<1, 256, 0, stream>>>(loss, (float*)d_out);
}